// Round 8
// baseline (187.842 us; speedup 1.0000x reference)
//
#include <hip/hip_runtime.h>

#define CMIN -1024.0f
#define CMAX 1016.0f

// Problem shape is fixed by the harness (asserted by rounds 0-6):
//   y: 16777216 floats = 4194304 float4   c: 8388608 floats = 2097152 float4
#define YNVEC   4194304
#define CNVEC   2097152
#define NTHR    524288          // 2048 blocks x 256 threads (8 blocks/CU)
#define DCPJ    32768           // DC count per c-slice (NTHR/16)
#define DC_PER_CH 65536

__device__ __forceinline__ float clampv(float x) {
    return fminf(fmaxf(x, CMIN), CMAX);
}

__device__ __forceinline__ float wave_reduce(float v) {
    #pragma unroll
    for (int off = 32; off > 0; off >>= 1)
        v += __shfl_down(v, off, 64);
    return v;
}

__device__ __forceinline__ float4 xform(float4 v) {
    float4 r;
    r.x = clampv(clampv(v.x) * 1.9f);
    r.y = clampv(clampv(v.y) * 1.9f);
    r.z = clampv(clampv(v.z) * 1.9f);
    r.w = clampv(clampv(v.w) * 1.9f);
    return r;
}

// ws layout: ws[0..2047]    = per-block ch0 DC partials
//            ws[2048..4095] = per-block ch1 DC partials
//            ws[4096..]     = compact pre-adjust DC values (131072 floats)

// ---------------------------------------------------------------------------
// Kernel 1: persistent-grid payload (m13-copy shape: 2048 blocks, strided
// slices, waves never die between batches -> preamble paid once, load stream
// never drains at block boundaries).
//   Thread t owns float4 indices {t + j*NTHR}: j=0..7 -> y, j=8..11 -> c.
//   Slicing by NTHR (multiple of 16) makes DC slots exactly the t%16==0
//   threads, and the channel of each c-slice is compile-time (j=8,9 -> ch0,
//   j=10,11 -> ch1): fully uniform control flow.
//   DC threads stash pre-adjust values into compact dcbuf and accumulate
//   clamped-DC partials; block reduces once at the end -> partials[b] (ch0)
//   and partials[2048+b] (ch1). Non-atomic, no memset. DC .x placeholders in
//   out are overwritten by kernel 2 (dispatch boundary orders the writers).
// ---------------------------------------------------------------------------
__global__ void __launch_bounds__(256)
payload(const float4* __restrict__ y4, const float4* __restrict__ c4,
        float4* __restrict__ out, float* __restrict__ partials,
        float* __restrict__ dcbuf)
{
    const int t   = threadIdx.x;
    const int tid = blockIdx.x * 256 + t;      // 0..524287

    // ---- y: 8 float4s, two 4-deep batches, no block death in between ----
    #pragma unroll
    for (int k = 0; k < 2; ++k) {
        const int g = tid + k * (4 * NTHR);
        float4 a = y4[g];
        float4 b = y4[g + NTHR];
        float4 c = y4[g + 2 * NTHR];
        float4 d = y4[g + 3 * NTHR];
        out[g]            = xform(a);
        out[g + NTHR]     = xform(b);
        out[g + 2 * NTHR] = xform(c);
        out[g + 3 * NTHR] = xform(d);
    }

    // ---- c: 4 float4s (ic = tid + j*NTHR, j=0..3), one 4-deep batch ----
    float4 v0 = c4[tid];
    float4 v1 = c4[tid + NTHR];
    float4 v2 = c4[tid + 2 * NTHR];
    float4 v3 = c4[tid + 3 * NTHR];

    float s0 = 0.0f, s1 = 0.0f;
    if ((t & 15) == 0) {                       // DC slots (tid%16==0)
        const int d0 = tid >> 4;               // DC index of slice j=0
        const float c0 = clampv(v0.x), c1 = clampv(v1.x);
        const float c2 = clampv(v2.x), c3 = clampv(v3.x);
        dcbuf[d0]            = c0 * 1.9f;      // pre-adjust, pre-final-clamp
        dcbuf[d0 + DCPJ]     = c1 * 1.9f;
        dcbuf[d0 + 2 * DCPJ] = c2 * 1.9f;
        dcbuf[d0 + 3 * DCPJ] = c3 * 1.9f;
        s0 = c0 + c1;                          // DC idx < 65536  -> channel 0
        s1 = c2 + c3;                          // DC idx >= 65536 -> channel 1
    }

    out[YNVEC + tid]            = xform(v0);   // DC .x = placeholder (K2 fixes)
    out[YNVEC + tid + NTHR]     = xform(v1);
    out[YNVEC + tid + 2 * NTHR] = xform(v2);
    out[YNVEC + tid + 3 * NTHR] = xform(v3);

    // ---- one block reduction at the end ----
    __shared__ float sm0[4], sm1[4];
    s0 = wave_reduce(s0);
    s1 = wave_reduce(s1);
    if ((t & 63) == 0) { sm0[t >> 6] = s0; sm1[t >> 6] = s1; }
    __syncthreads();
    if (t == 0) {
        partials[blockIdx.x]        = sm0[0] + sm0[1] + sm0[2] + sm0[3];
        partials[2048 + blockIdx.x] = sm1[0] + sm1[1] + sm1[2] + sm1[3];
    }
}

// ---------------------------------------------------------------------------
// Kernel 2: micro-fixup. 512 blocks x 256 threads, one DC each.
//   Compact dcbuf load issues first; the 4096-partial reduce (16 KB,
//   L2-resident) hides under it. One scattered 4 B store per thread.
// ---------------------------------------------------------------------------
__global__ void __launch_bounds__(256)
dc_fixup(float* __restrict__ outc, const float* __restrict__ partials,
         const float* __restrict__ dcbuf, float neg09_inv_count)
{
    const int t = threadIdx.x;
    const int d = blockIdx.x * 256 + t;        // DC index 0..131071

    const float pre = dcbuf[d];                // issue payload load first

    float s0 = 0.0f, s1 = 0.0f;
    #pragma unroll
    for (int j = 0; j < 2048; j += 256) {
        s0 += partials[t + j];
        s1 += partials[2048 + t + j];
    }
    s0 = wave_reduce(s0);
    s1 = wave_reduce(s1);

    __shared__ float sm[8];
    __shared__ float sadj[2];
    const int lane = t & 63;
    const int wave = t >> 6;
    if (lane == 0) { sm[wave] = s0; sm[4 + wave] = s1; }
    __syncthreads();
    if (t == 0) {
        sadj[0] = (sm[0] + sm[1] + sm[2] + sm[3]) * neg09_inv_count;
        sadj[1] = (sm[4] + sm[5] + sm[6] + sm[7]) * neg09_inv_count;
    }
    __syncthreads();

    const float adj = (d < DC_PER_CH) ? sadj[0] : sadj[1];
    outc[(size_t)d * 64] = clampv(pre + adj);
}

extern "C" void kernel_launch(void* const* d_in, const int* in_sizes, int n_in,
                              void* d_out, int out_size, void* d_ws, size_t ws_size,
                              hipStream_t stream) {
    const float* y = (const float*)d_in[0];
    const float* c = (const float*)d_in[1];
    float* out = (float*)d_out;
    float* ws  = (float*)d_ws;

    float* partials = ws;                      // 4096 floats
    float* dcbuf    = ws + 4096;               // 131072 floats

    const float neg09_inv_count = -0.9f / (float)DC_PER_CH;

    // Kernel 1: persistent-grid payload (2048 blocks = 8/CU exactly)
    payload<<<2048, 256, 0, stream>>>(
        (const float4*)y, (const float4*)c, (float4*)out, partials, dcbuf);

    // Kernel 2: micro fixup of the 131072 DC outputs
    dc_fixup<<<512, 256, 0, stream>>>(
        out + (size_t)YNVEC * 4, partials, dcbuf, neg09_inv_count);
}

// Round 11
// 181.142 us; speedup vs baseline: 1.0370x; 1.0370x over previous
//
#include <hip/hip_runtime.h>

#define CMIN -1024.0f
#define CMAX 1016.0f

// native clang vector type: bit-identical to float4, accepted by
// __builtin_nontemporal_store (HIP_vector_type is a struct and is not)
typedef float f4 __attribute__((ext_vector_type(4)));

__device__ __forceinline__ float clampv(float x) {
    return fminf(fmaxf(x, CMIN), CMAX);
}

__device__ __forceinline__ float wave_reduce(float v) {
    #pragma unroll
    for (int off = 32; off > 0; off >>= 1)
        v += __shfl_down(v, off, 64);
    return v;
}

__device__ __forceinline__ float4 xform(float4 v) {
    float4 r;
    r.x = clampv(clampv(v.x) * 1.9f);
    r.y = clampv(clampv(v.y) * 1.9f);
    r.z = clampv(clampv(v.z) * 1.9f);
    r.w = clampv(clampv(v.w) * 1.9f);
    return r;
}

__device__ __forceinline__ void nt_store4(float4 v, float4* p) {
    union { float4 s; f4 n; } u;
    u.s = v;
    __builtin_nontemporal_store(u.n, (f4*)p);
}

// ---------------------------------------------------------------------------
// Kernel 1: copy-pure payload (r6's proven 4-deep one-shot shape, riders
// stripped).
//   y-blocks [0,4096):  out = clamp(clamp(y)*1.9) via NON-TEMPORAL stores --
//     y writes bypass L2/L3 so the L3-resident input isn't evicted by
//     write-allocate (theory: that eviction is why FETCH=50MB of a 100MB
//     logical read stream).
//   c-blocks [4096,6144): same transform, NORMAL stores (K2 rewrites .x of DC
//     float4s with scattered 4B stores -> those lines must stay L2-resident
//     to avoid partial-line RMW from HBM). Only rider kept: the zero-traffic
//     per-block DC partial sum. No dcbuf stash -- K2 re-gathers DC values
//     from the L3-resident input instead (r0 measured this gather at ~3us).
//   partials[0..1023] = ch0 (c-block cb<1024 covers DC < 65536),
//   partials[1024..2047] = ch1. Non-atomic, no memset.
// ---------------------------------------------------------------------------
__global__ void __launch_bounds__(256)
payload(const float4* __restrict__ y4, const float4* __restrict__ c4,
        float4* __restrict__ out, float* __restrict__ partials,
        int yblocks, int ynvec)
{
    const int b = blockIdx.x;
    const int t = threadIdx.x;

    if (b < yblocks) {
        const int base = b * 1024 + t;
        float4 a  = y4[base];
        float4 v1 = y4[base + 256];
        float4 v2 = y4[base + 512];
        float4 v3 = y4[base + 768];
        nt_store4(xform(a),  &out[base]);
        nt_store4(xform(v1), &out[base + 256]);
        nt_store4(xform(v2), &out[base + 512]);
        nt_store4(xform(v3), &out[base + 768]);
        return;
    }

    // ---- c tile ----
    const int cb   = b - yblocks;            // 0..2047
    const int base = cb * 1024 + t;
    float4 v0 = c4[base];
    float4 v1 = c4[base + 256];
    float4 v2 = c4[base + 512];
    float4 v3 = c4[base + 768];

    float part = 0.0f;
    if ((t & 15) == 0)                       // DC slots (base%16==0 <=> t%16==0)
        part = clampv(v0.x) + clampv(v1.x) + clampv(v2.x) + clampv(v3.x);

    out[ynvec + base]       = xform(v0);     // DC .x = placeholder (K2 fixes)
    out[ynvec + base + 256] = xform(v1);
    out[ynvec + base + 512] = xform(v2);
    out[ynvec + base + 768] = xform(v3);

    __shared__ float sm[4];
    float s = wave_reduce(part);
    if ((t & 63) == 0) sm[t >> 6] = s;
    __syncthreads();
    if (t == 0) partials[cb] = sm[0] + sm[1] + sm[2] + sm[3];
}

// ---------------------------------------------------------------------------
// Kernel 2: all remaining DC work. 512 blocks x 256 threads, one DC each.
//   Gather clamped DC from the L3-resident INPUT (issued first), reduce the
//   2048 L2-resident partials under it, then one scattered 4B store per
//   thread into the L2-resident c-output lines K1 just wrote.
// ---------------------------------------------------------------------------
__global__ void __launch_bounds__(256)
dc_fixup(const float* __restrict__ cf, float* __restrict__ outc,
         const float* __restrict__ partials, int dc_per_ch,
         float neg09_inv_count)
{
    const int t = threadIdx.x;
    const int d = blockIdx.x * 256 + t;      // DC index 0..131071

    // issue the gather first
    const float pre = clampv(cf[(size_t)d * 64]) * 1.9f;

    float s0 = partials[t] + partials[t + 256] +
               partials[t + 512] + partials[t + 768];
    float s1 = partials[1024 + t] + partials[1280 + t] +
               partials[1536 + t] + partials[1792 + t];
    s0 = wave_reduce(s0);
    s1 = wave_reduce(s1);

    __shared__ float sm[8];
    __shared__ float sadj[2];
    const int lane = t & 63;
    const int wave = t >> 6;
    if (lane == 0) { sm[wave] = s0; sm[4 + wave] = s1; }
    __syncthreads();
    if (t == 0) {
        sadj[0] = (sm[0] + sm[1] + sm[2] + sm[3]) * neg09_inv_count;
        sadj[1] = (sm[4] + sm[5] + sm[6] + sm[7]) * neg09_inv_count;
    }
    __syncthreads();

    const float adj = (d < dc_per_ch) ? sadj[0] : sadj[1];
    outc[(size_t)d * 64] = clampv(pre + adj);
}

extern "C" void kernel_launch(void* const* d_in, const int* in_sizes, int n_in,
                              void* d_out, int out_size, void* d_ws, size_t ws_size,
                              hipStream_t stream) {
    const float* y = (const float*)d_in[0];
    const float* c = (const float*)d_in[1];
    float* out = (float*)d_out;
    float* ws  = (float*)d_ws;

    const int yN = in_sizes[0];             // 16777216 floats
    const int cN = in_sizes[1];             // 8388608 floats

    const int ynvec     = yN / 4;           // 4194304 float4
    const int cnvec     = cN / 4;           // 2097152 float4
    const int yblocks   = ynvec / 1024;     // 4096
    const int cblocks   = cnvec / 1024;     // 2048
    const int dc_count  = cN / 64;          // 131072
    const int dc_per_ch = dc_count / 2;     // 65536
    const float neg09_inv_count = -0.9f / (float)dc_per_ch;

    float* partials = ws;                   // 2048 floats

    payload<<<yblocks + cblocks, 256, 0, stream>>>(
        (const float4*)y, (const float4*)c, (float4*)out, partials,
        yblocks, ynvec);

    dc_fixup<<<512, 256, 0, stream>>>(
        c, out + (size_t)yN, partials, dc_per_ch, neg09_inv_count);
}